// Round 7
// baseline (184.525 us; speedup 1.0000x reference)
//
#include <hip/hip_runtime.h>

// Attention: B=256,H=16,NQ=NK=49,D=64, fp32 in/out. One block per (b,h).
// R11 = R10 + NONTEMPORAL O stores. A/B experiment, everything else
// byte-identical to R10.
// Cross-round invariant (R4-R10): five structurally different kernels
// (staged/barriered, double-buffered, barrier-free gather, region-fenced;
// occupancy 23-67%) all land at 68-77us with FETCH_SIZE frozen at 75.3MB,
// WRITE_SIZE at 50.2MB, hbm ~1.8TB/s. Theory: the 205MB working set cycles
// the 256MB L3 every dispatch; O's 51MB write-allocate evicts Q/K/V, forcing
// ~75MB of HBM re-fetch per iteration -> dispatch time = HBM miss-stream
// service time, independent of kernel structure. Fix under test: nt stores
// for O (no cache allocation) -> inputs stay L3-resident across dispatches.
// Falsifier: FETCH unchanged => nt ineffective (void); FETCH down + time
// flat => latency-bound on L3 hits (theory dead, pivot).
// Kept from R10: direct-from-global K/Q frags, scalar-column V frags,
// sched_barrier(0) region fencing, wave-private P tile in LDS, no-max
// softmax, pad col masking, address clamps, zero s_barrier.

#define NQA 49
#define DD  64
#define PST 72   // P row stride (bf16): 144B -> b128 reads 2-way conflict (free)

typedef __bf16 bf16x8 __attribute__((ext_vector_type(8)));
typedef float  f32x4  __attribute__((ext_vector_type(4)));

__global__ __launch_bounds__(256, 4)
void attn49_kernel(const float* __restrict__ Q, const float* __restrict__ K,
                   const float* __restrict__ V, float* __restrict__ O) {
    __shared__ __bf16 P[4][16 * PST];   // wave-private P tiles (9216 B total)

    const int tid = threadIdx.x;
    const int w  = tid >> 6;        // wave 0..3 owns q-rows 16w..16w+15
    const int lr = tid & 15;
    const int lg = (tid >> 4) & 3;  // quad

    const size_t base = (size_t)blockIdx.x * (NQA * DD);
    const float* Qg = Q + base;
    const float* Kg = K + base;
    const float* Vg = V + base;

    // ================= region 1: issue Q + all K loads =================
    float4 qv[4];
    {
        const int qrow = 16*w + lr;
        const int qc   = (qrow < NQA) ? qrow : (NQA - 1);
        const float* Qr = Qg + qc * DD + 8 * lg;
        qv[0] = *(const float4*)(Qr + 0);
        qv[1] = *(const float4*)(Qr + 4);
        qv[2] = *(const float4*)(Qr + 32);
        qv[3] = *(const float4*)(Qr + 36);
    }
    float4 kf[16];
    #pragma unroll
    for (int t = 0; t < 4; ++t) {
        const int kr = 16*t + lr;
        const int kc = (kr < NQA) ? kr : (NQA - 1);   // dup row 48; masked below
        const float* Kr = Kg + kc * DD + 8 * lg;
        kf[4*t + 0] = *(const float4*)(Kr + 0);
        kf[4*t + 1] = *(const float4*)(Kr + 4);
        kf[4*t + 2] = *(const float4*)(Kr + 32);
        kf[4*t + 3] = *(const float4*)(Kr + 36);
    }
    __builtin_amdgcn_sched_barrier(0);

    // ================= region 2: phase-1 MFMA =========================
    bf16x8 aq0 = { (__bf16)(0.125f*qv[0].x), (__bf16)(0.125f*qv[0].y),
                   (__bf16)(0.125f*qv[0].z), (__bf16)(0.125f*qv[0].w),
                   (__bf16)(0.125f*qv[1].x), (__bf16)(0.125f*qv[1].y),
                   (__bf16)(0.125f*qv[1].z), (__bf16)(0.125f*qv[1].w) };
    bf16x8 aq1 = { (__bf16)(0.125f*qv[2].x), (__bf16)(0.125f*qv[2].y),
                   (__bf16)(0.125f*qv[2].z), (__bf16)(0.125f*qv[2].w),
                   (__bf16)(0.125f*qv[3].x), (__bf16)(0.125f*qv[3].y),
                   (__bf16)(0.125f*qv[3].z), (__bf16)(0.125f*qv[3].w) };
    f32x4 acc[4] = {};
    #pragma unroll
    for (int t = 0; t < 4; ++t) {
        float4 a = kf[4*t + 0], b = kf[4*t + 1],
               c = kf[4*t + 2], d = kf[4*t + 3];
        bf16x8 kb0 = { (__bf16)a.x, (__bf16)a.y, (__bf16)a.z, (__bf16)a.w,
                       (__bf16)b.x, (__bf16)b.y, (__bf16)b.z, (__bf16)b.w };
        bf16x8 kb1 = { (__bf16)c.x, (__bf16)c.y, (__bf16)c.z, (__bf16)c.w,
                       (__bf16)d.x, (__bf16)d.y, (__bf16)d.z, (__bf16)d.w };
        acc[t] = __builtin_amdgcn_mfma_f32_16x16x32_bf16(aq0, kb0, acc[t], 0, 0, 0);
        acc[t] = __builtin_amdgcn_mfma_f32_16x16x32_bf16(aq1, kb1, acc[t], 0, 0, 0);
    }
    __builtin_amdgcn_sched_barrier(0);

    // ================= region 3: issue all 64 V loads =================
    // lane (lr,lg) needs V[8lg+j+32h][16t+lr]; rows clamped to <=48 (the
    // clamped duplicates multiply P=0 pad cols -> contribute nothing).
    float vf[64];
    #pragma unroll
    for (int t = 0; t < 4; ++t) {
        const float* Vc = Vg + 16*t + lr;
        #pragma unroll
        for (int h = 0; h < 2; ++h) {
            #pragma unroll
            for (int j = 0; j < 8; ++j) {
                const int vr = 32*h + 8*lg + j;
                const int vc = (vr < NQA) ? vr : (NQA - 1);
                vf[16*t + 8*h + j] = Vc[vc * DD];
            }
        }
    }
    __builtin_amdgcn_sched_barrier(0);

    // ================= region 4: softmax + P roundtrip ================
    // Lane: rows 16w+4lg+ii, col 16t+lr. Pad cols 49..63 masked (e3 only
    // at lr==0 = col 48). V latency hides under this region.
    __bf16* Pw = &P[w][0];
    float inv_l[4];
    #pragma unroll
    for (int ii = 0; ii < 4; ++ii) {
        float e0 = __expf(acc[0][ii]);
        float e1 = __expf(acc[1][ii]);
        float e2 = __expf(acc[2][ii]);
        float e3 = (lr == 0) ? __expf(acc[3][ii]) : 0.f;
        float sum = (e0 + e1) + (e2 + e3);
        #pragma unroll
        for (int d = 1; d < 16; d <<= 1) sum += __shfl_xor(sum, d, 64);
        inv_l[ii] = 1.f / (sum + 1e-9f);
        const int pr = 4*lg + ii;            // row within this wave's P tile
        Pw[pr * PST +  0 + lr] = (__bf16)e0;
        Pw[pr * PST + 16 + lr] = (__bf16)e1;
        Pw[pr * PST + 32 + lr] = (__bf16)e2;
        Pw[pr * PST + 48 + lr] = (__bf16)e3;  // cols 49..63 = 0
    }
    // P A-frags from wave-private LDS (no barrier: own-wave RAW; compiler
    // inserts the lgkmcnt wait).
    bf16x8 ap0 = *(const bf16x8*)&Pw[lr * PST      + 8*lg];
    bf16x8 ap1 = *(const bf16x8*)&Pw[lr * PST + 32 + 8*lg];

    // ================= region 5: phase-2 MFMA + nt store ==============
    f32x4 oacc[4] = {};
    #pragma unroll
    for (int t = 0; t < 4; ++t) {
        #pragma unroll
        for (int h = 0; h < 2; ++h) {
            bf16x8 vb;
            #pragma unroll
            for (int j = 0; j < 8; ++j)
                vb[j] = (__bf16)vf[16*t + 8*h + j];
            oacc[t] = __builtin_amdgcn_mfma_f32_16x16x32_bf16(
                          h ? ap1 : ap0, vb, oacc[t], 0, 0, 0);
        }
    }

    // Nontemporal: O is write-once, never re-read by this kernel. Avoids
    // write-allocate evicting Q/K/V from L2/L3 between dispatches (the
    // theory under test: FETCH_SIZE should drop 75MB -> ~25-55MB).
    float* Og = O + base;
    #pragma unroll
    for (int ii = 0; ii < 4; ++ii) {
        const int gq = 16*w + 4*lg + ii;
        if (gq < NQA) {
            #pragma unroll
            for (int t = 0; t < 4; ++t)
                __builtin_nontemporal_store(oacc[t][ii] * inv_l[ii],
                                            &Og[gq * DD + 16*t + lr]);
        }
    }
}

extern "C" void kernel_launch(void* const* d_in, const int* in_sizes, int n_in,
                              void* d_out, int out_size, void* d_ws, size_t ws_size,
                              hipStream_t stream) {
    const float* q = (const float*)d_in[0];
    const float* k = (const float*)d_in[1];
    const float* v = (const float*)d_in[2];
    float* out = (float*)d_out;
    (void)in_sizes; (void)n_in; (void)out_size; (void)d_ws; (void)ws_size;
    attn49_kernel<<<dim3(4096), dim3(256), 0, stream>>>(q, k, v, out);
}